// Round 5
// baseline (906.745 us; speedup 1.0000x reference)
//
#include <hip/hip_runtime.h>
#include <hip/hip_bf16.h>
#include <hip/hip_cooperative_groups.h>
namespace cg = cooperative_groups;

#define BATCH 8192
#define IN_DIM 64
#define HID 1024
#define KTOT 1088   // HID + IN_DIM, fused K
#define NGATES 4096 // 4*HID, column c = 64*G + 16*g + q -> gate g of h=16*G+q
#define OMID 128
#define NP 256      // packed P rows (W1 0..127, W_halt 128, zeros)
#define MAX_ITER 8

#define TM 128
#define TN 128
#define TK 64

typedef __attribute__((ext_vector_type(8))) short short8;
typedef __attribute__((ext_vector_type(4))) float float4v;

__device__ __forceinline__ float bf2f(short s) {
    union { float f; unsigned u; } v; v.u = ((unsigned)(unsigned short)s) << 16; return v.f;
}
__device__ __forceinline__ short f2bf(float f) {
    union { float f; unsigned u; } v; v.f = f;
    unsigned r = v.u + 0x7fff + ((v.u >> 16) & 1);  // round-to-nearest-even
    return (short)(r >> 16);
}
__device__ __forceinline__ float sigmoidf_(float x) {
    float xc = fminf(fmaxf(x, -30.f), 30.f);
    return 1.f / (1.f + __expf(-xc));
}
__device__ __forceinline__ float tanhf_(float x) {
    float xc = fminf(fmaxf(x, -15.f), 15.f);
    float e = __expf(2.f * xc);
    return (e - 1.f) / (e + 1.f);
}

struct PK {
    const short* Wg; const float* bias_g;
    const short* P;  const float* bias_p;
    const float* W_halt; const float* W2; const float* b2;
    short* A0; short* A1; float* cell; float* p_sum;
    int* ridx0; int* ridx1; int* cnt; float* outp;
};

// Persistent cooperative kernel: full 8-step ACT loop, 2 grid syncs per
// live step. Phase A = gates GEMM (fused LSTM cell update epilogue, R2's
// verified LDS XOR swizzle -> 0 bank conflicts). Phase B = mid GEMM
// (cols 0..127 = W1) with W2-dot fused via shuffle+LDS reduction, halt
// h via direct state·W_halt wave dot, and full halting bookkeeping.
// Steps with cnt[t]==0 skip work AND syncs (uniform across grid).
__global__ __launch_bounds__(256, 4) void act_loop(PK p) {
    __shared__ short As[TM * TK];
    __shared__ short Bs[TN * TK];
    __shared__ float red[2][2][4][4][4];   // [wn][wm][i][q][r]
    __shared__ float hbuf[TM];
    cg::grid_group grid = cg::this_grid();

    const int tid  = threadIdx.x;
    const int wave = tid >> 6, lane = tid & 63;
    const int wm = wave & 1, wn = wave >> 1;
    const int colq = lane & 15;
    const int q    = lane >> 4;
    const int lrow8 = lane >> 3;                    // row within 8-row region
    const int lk    = (((lane & 7) ^ lrow8) * 8);   // swizzled source k-chunk

    for (int t = 0; t < MAX_ITER; ++t) {
        const short* Ain = (t & 1) ? p.A1 : p.A0;
        short*       Aot = (t & 1) ? p.A0 : p.A1;
        const int* rc = (t & 1) ? p.ridx1 : p.ridx0;
        int*       rn = (t & 1) ? p.ridx0 : p.ridx1;
        const int n_act = __hip_atomic_load(&p.cnt[t], __ATOMIC_RELAXED,
                                            __HIP_MEMORY_SCOPE_AGENT);
        if (n_act == 0) continue;   // uniform: all blocks skip work + syncs
        const int mt = (n_act + TM - 1) / TM;

        // ---------------- Phase A: gates GEMM + cell update ----------------
        {
            // t=0: state==0, only the x-part (K=64) of fused K contributes
            const short* Ause = (t == 0) ? Ain + HID : Ain;
            const short* Buse = (t == 0) ? p.Wg + HID : p.Wg;
            const int Kuse = (t == 0) ? IN_DIM : KTOT;
            const int ntiles = mt * (NGATES / TN);
            for (int tile = blockIdx.x; tile < ntiles; tile += gridDim.x) {
                const int bx = tile & 31, by = tile >> 5;
                const int m0 = by * TM, n0 = bx * TN;

                float4v acc[4][4];
#pragma unroll
                for (int i = 0; i < 4; ++i)
#pragma unroll
                    for (int j = 0; j < 4; ++j) acc[i][j] = (float4v)0.f;

                int arows[4];
#pragma unroll
                for (int it = 0; it < 4; ++it)
                    arows[it] = rc[m0 + (wave * 4 + it) * 8 + lrow8];

                for (int k0 = 0; k0 < Kuse; k0 += TK) {
#pragma unroll
                    for (int it = 0; it < 4; ++it) {
                        const int rr = (wave * 4 + it) * 8;
                        const short* ga = Ause + (size_t)arows[it] * KTOT + k0 + lk;
                        __builtin_amdgcn_global_load_lds(
                            (const __attribute__((address_space(1))) void*)ga,
                            (__attribute__((address_space(3))) void*)(As + rr * TK), 16, 0, 0);
                        const short* gb = Buse + (size_t)(n0 + rr + lrow8) * KTOT + k0 + lk;
                        __builtin_amdgcn_global_load_lds(
                            (const __attribute__((address_space(1))) void*)gb,
                            (__attribute__((address_space(3))) void*)(Bs + rr * TK), 16, 0, 0);
                    }
                    __syncthreads();
#pragma unroll
                    for (int kk = 0; kk < TK; kk += 32) {
                        short8 af[4], bf[4];
#pragma unroll
                        for (int i = 0; i < 4; ++i) {
                            const int Ra = wm * 64 + i * 16 + colq;
                            const int Rb = wn * 64 + i * 16 + colq;
                            const int C  = (kk >> 3) + q;
                            af[i] = *(const short8*)(As + Ra * TK + ((C ^ (Ra & 7)) << 3));
                            bf[i] = *(const short8*)(Bs + Rb * TK + ((C ^ (Rb & 7)) << 3));
                        }
#pragma unroll
                        for (int i = 0; i < 4; ++i)
#pragma unroll
                            for (int j = 0; j < 4; ++j)
                                acc[i][j] = __builtin_amdgcn_mfma_f32_16x16x32_bf16(af[i], bf[j], acc[i][j], 0, 0, 0);
                    }
                    __syncthreads();
                }

                const int G = bx * 2 + wn;   // 64-col group = 16 hidden units
                const int h = G * 16 + colq;
                const float bi  = p.bias_g[G * 64 +  0 + colq];
                const float bff = p.bias_g[G * 64 + 16 + colq];
                const float bc  = p.bias_g[G * 64 + 32 + colq];
                const float bo  = p.bias_g[G * 64 + 48 + colq];
#pragma unroll
                for (int i = 0; i < 4; ++i) {
                    const int pbase = m0 + wm * 64 + i * 16 + q * 4;
#pragma unroll
                    for (int r = 0; r < 4; ++r) {
                        const int pos = pbase + r;
                        if (pos < n_act) {
                            const int row = rc[pos];
                            const float ig = sigmoidf_(acc[i][0][r] + bi);
                            const float fg = sigmoidf_(acc[i][1][r] + bff);
                            const float cg = tanhf_(acc[i][2][r] + bc);
                            const float og = sigmoidf_(acc[i][3][r] + bo);
                            const size_t ci = (size_t)row * HID + h;
                            const float c = fg * p.cell[ci] + ig * cg;
                            p.cell[ci] = c;
                            Aot[(size_t)row * KTOT + h] = f2bf(og * tanhf_(c));
                        }
                    }
                }
            }
        }
        grid.sync();

        // -------- Phase B: mid GEMM + W2-dot + halt + finalize --------
        for (int by = blockIdx.x; by < mt; by += gridDim.x) {
            const int m0 = by * TM;

            // (1) h-dot: per row, state · W_halt (fp32 weights, global reads)
            for (int s = 0; s < 32; ++s) {
                const int lr = wave * 32 + s;
                const int row = rc[m0 + lr];
                const short* Ar = Aot + (size_t)row * KTOT + lane * 16;
                const short8 v0 = *(const short8*)Ar;
                const short8 v1 = *(const short8*)(Ar + 8);
                const float* Wh = p.W_halt + lane * 16;
                float hv = 0.f;
#pragma unroll
                for (int e = 0; e < 8; ++e) hv += bf2f(v0[e]) * Wh[e];
#pragma unroll
                for (int e = 0; e < 8; ++e) hv += bf2f(v1[e]) * Wh[8 + e];
#pragma unroll
                for (int o = 32; o > 0; o >>= 1) hv += __shfl_down(hv, o);
                if (lane == 0) hbuf[lr] = hv;
            }

            // (2) mid GEMM tile: cols 0..127 (W1), K = HID
            float4v acc[4][4];
#pragma unroll
            for (int i = 0; i < 4; ++i)
#pragma unroll
                for (int j = 0; j < 4; ++j) acc[i][j] = (float4v)0.f;
            int arows[4];
#pragma unroll
            for (int it = 0; it < 4; ++it)
                arows[it] = rc[m0 + (wave * 4 + it) * 8 + lrow8];

            for (int k0 = 0; k0 < HID; k0 += TK) {
#pragma unroll
                for (int it = 0; it < 4; ++it) {
                    const int rr = (wave * 4 + it) * 8;
                    const short* ga = Aot + (size_t)arows[it] * KTOT + k0 + lk;
                    __builtin_amdgcn_global_load_lds(
                        (const __attribute__((address_space(1))) void*)ga,
                        (__attribute__((address_space(3))) void*)(As + rr * TK), 16, 0, 0);
                    const short* gb = p.P + (size_t)(rr + lrow8) * HID + k0 + lk;
                    __builtin_amdgcn_global_load_lds(
                        (const __attribute__((address_space(1))) void*)gb,
                        (__attribute__((address_space(3))) void*)(Bs + rr * TK), 16, 0, 0);
                }
                __syncthreads();
#pragma unroll
                for (int kk = 0; kk < TK; kk += 32) {
                    short8 af[4], bf[4];
#pragma unroll
                    for (int i = 0; i < 4; ++i) {
                        const int Ra = wm * 64 + i * 16 + colq;
                        const int Rb = wn * 64 + i * 16 + colq;
                        const int C  = (kk >> 3) + q;
                        af[i] = *(const short8*)(As + Ra * TK + ((C ^ (Ra & 7)) << 3));
                        bf[i] = *(const short8*)(Bs + Rb * TK + ((C ^ (Rb & 7)) << 3));
                    }
#pragma unroll
                    for (int i = 0; i < 4; ++i)
#pragma unroll
                        for (int j = 0; j < 4; ++j)
                            acc[i][j] = __builtin_amdgcn_mfma_f32_16x16x32_bf16(af[i], bf[j], acc[i][j], 0, 0, 0);
                }
                __syncthreads();
            }

            // (3) epilogue: relu + W2-dot, reduce over cols
            float pr[4][4];
#pragma unroll
            for (int i = 0; i < 4; ++i)
#pragma unroll
                for (int r = 0; r < 4; ++r) pr[i][r] = 0.f;
#pragma unroll
            for (int j = 0; j < 4; ++j) {
                const int col = wn * 64 + j * 16 + colq;
                const float b = p.bias_p[col];
                const float w2 = p.W2[col];
#pragma unroll
                for (int i = 0; i < 4; ++i)
#pragma unroll
                    for (int r = 0; r < 4; ++r)
                        pr[i][r] += fmaxf(acc[i][j][r] + b, 0.f) * w2;
            }
#pragma unroll
            for (int i = 0; i < 4; ++i)
#pragma unroll
                for (int r = 0; r < 4; ++r) {
                    float v = pr[i][r];
                    v += __shfl_down(v, 8, 16);
                    v += __shfl_down(v, 4, 16);
                    v += __shfl_down(v, 2, 16);
                    v += __shfl_down(v, 1, 16);
                    if (colq == 0) red[wn][wm][i][q][r] = v;
                }
            __syncthreads();

            // (4) finalize: one thread per row
            if (tid < TM) {
                const int pos = m0 + tid;
                if (pos < n_act) {
                    const int lwm = tid >> 6, i = (tid >> 4) & 3, lq = (tid >> 2) & 3, r = tid & 3;
                    const float odot = red[0][lwm][i][lq][r] + red[1][lwm][i][lq][r];
                    const int row = rc[pos];
                    const float ov = sigmoidf_(odot + p.b2[0]);
                    const float h  = sigmoidf_(hbuf[tid] + p.bias_p[OMID]);
                    const float ps = p.p_sum[row];
                    const float pn = ps + h;
                    const bool fin = (pn >= 1.f - 1e-3f) || (t == MAX_ITER - 1);
                    const float halt = fin ? (1.f - ps) : h;
                    p.outp[row] += ov * halt;
                    p.p_sum[row] = fin ? 1.f : pn;
                    if (!fin) {
                        const int d = atomicAdd(&p.cnt[t + 1], 1);
                        rn[d] = row;
                    }
                }
            }
            __syncthreads();   // before next tile reuses As/Bs/red/hbuf
        }
        grid.sync();
    }
}

// one dispatch for all setup: weight packing + A/cell/bookkeeping init
#define SETUP_INIT  (BATCH * KTOT)
#define SETUP_WG    (NGATES * KTOT)
#define SETUP_P     (NP * HID)
#define SETUP_TOT   (SETUP_INIT + SETUP_WG + SETUP_P)
__global__ __launch_bounds__(256) void setup_k(
    const float* __restrict__ x,
    const float* __restrict__ Whi, const float* __restrict__ Whf,
    const float* __restrict__ Whc, const float* __restrict__ Who,
    const float* __restrict__ Wxi, const float* __restrict__ Wxf,
    const float* __restrict__ Wxc, const float* __restrict__ Wxo,
    const float* __restrict__ bxi, const float* __restrict__ bhi,
    const float* __restrict__ bxf, const float* __restrict__ bhf,
    const float* __restrict__ bxc, const float* __restrict__ bhc,
    const float* __restrict__ bxo, const float* __restrict__ bho,
    const float* __restrict__ W1, const float* __restrict__ b1,
    const float* __restrict__ W_halt, const float* __restrict__ b_halt,
    short* __restrict__ A0, short* __restrict__ A1,
    float* __restrict__ cell, float* __restrict__ p_sum,
    int* __restrict__ ridx0, int* __restrict__ ridx1, int* __restrict__ cnt,
    float* __restrict__ outp,
    short* __restrict__ Wg, float* __restrict__ bias_g,
    short* __restrict__ P, float* __restrict__ bias_p)
{
    int idx = blockIdx.x * 256 + threadIdx.x;
    if (idx < SETUP_INIT) {
        const int row = idx / KTOT, k = idx - row * KTOT;
        const short v = (k < HID) ? (short)0 : f2bf(x[row * IN_DIM + (k - HID)]);
        A0[idx] = v;
        A1[idx] = v;   // x cols iteration-invariant; state part overwritten each step
        if (k < HID) cell[(size_t)row * HID + k] = 0.f;
        if (k == 0) {
            p_sum[row] = 0.f;
            outp[row] = 0.f;
            ridx0[row] = row;   // step 0: identity compaction
            ridx1[row] = 0;     // in-range dummies for padded tile reads
        }
        if (row == 0 && k <= MAX_ITER) cnt[k] = (k == 0) ? BATCH : 0;
        return;
    }
    idx -= SETUP_INIT;
    if (idx < SETUP_WG) {
        const int n = idx / KTOT, k = idx - n * KTOT;
        // interleaved layout: n = 64*G + 16*g + q  ->  gate g of hidden h=16*G+q
        const int G = n >> 6, g = (n >> 4) & 3, q = n & 15;
        const int h = G * 16 + q;
        const float* Wh = (g == 0) ? Whi : (g == 1) ? Whf : (g == 2) ? Whc : Who;
        const float* Wx = (g == 0) ? Wxi : (g == 1) ? Wxf : (g == 2) ? Wxc : Wxo;
        const float v = (k < HID) ? Wh[h * HID + k] : Wx[h * IN_DIM + (k - HID)];
        Wg[idx] = f2bf(v);
        if (k == 0) {
            const float* bx = (g == 0) ? bxi : (g == 1) ? bxf : (g == 2) ? bxc : bxo;
            const float* bh = (g == 0) ? bhi : (g == 1) ? bhf : (g == 2) ? bhc : bho;
            bias_g[n] = bx[h] + bh[h];
        }
        return;
    }
    idx -= SETUP_WG;
    if (idx < SETUP_P) {
        const int n = idx >> 10, k = idx & 1023;
        const float v = (n < OMID) ? W1[n * HID + k] : (n == OMID ? W_halt[k] : 0.f);
        P[idx] = f2bf(v);
        if (k == 0) bias_p[n] = (n < OMID) ? b1[n] : (n == OMID ? b_halt[0] : 0.f);
    }
}

extern "C" void kernel_launch(void* const* d_in, const int* in_sizes, int n_in,
                              void* d_out, int out_size, void* d_ws, size_t ws_size,
                              hipStream_t stream) {
    const float* x    = (const float*)d_in[0];
    const float* Wxi  = (const float*)d_in[1];
    const float* bxi  = (const float*)d_in[2];
    const float* Whi  = (const float*)d_in[3];
    const float* bhi  = (const float*)d_in[4];
    const float* Wxf  = (const float*)d_in[5];
    const float* bxf  = (const float*)d_in[6];
    const float* Whf  = (const float*)d_in[7];
    const float* bhf  = (const float*)d_in[8];
    const float* Wxc  = (const float*)d_in[9];
    const float* bxc  = (const float*)d_in[10];
    const float* Whc  = (const float*)d_in[11];
    const float* bhc  = (const float*)d_in[12];
    const float* Wxo  = (const float*)d_in[13];
    const float* bxo  = (const float*)d_in[14];
    const float* Who  = (const float*)d_in[15];
    const float* bho  = (const float*)d_in[16];
    const float* W_halt = (const float*)d_in[17];
    const float* b_halt = (const float*)d_in[18];
    const float* W1   = (const float*)d_in[19];
    const float* b1   = (const float*)d_in[20];
    const float* W2   = (const float*)d_in[21];
    const float* b2   = (const float*)d_in[22];

    char* p = (char*)d_ws;
    auto carve = [&](size_t bytes) { char* r = p; p += (bytes + 255) & ~(size_t)255; return r; };
    short* A0     = (short*)carve((size_t)BATCH * KTOT * 2);
    short* A1     = (short*)carve((size_t)BATCH * KTOT * 2);
    short* Wg     = (short*)carve((size_t)NGATES * KTOT * 2);
    float* bias_g = (float*)carve((size_t)NGATES * 4);
    short* P      = (short*)carve((size_t)NP * HID * 2);
    float* bias_p = (float*)carve((size_t)NP * 4);
    float* cell   = (float*)carve((size_t)BATCH * HID * 4);
    float* p_sum  = (float*)carve((size_t)BATCH * 4);
    int*   ridx0  = (int*)carve((size_t)BATCH * 4);
    int*   ridx1  = (int*)carve((size_t)BATCH * 4);
    int*   cnt    = (int*)carve((size_t)(MAX_ITER + 1) * 4);

    setup_k<<<(SETUP_TOT + 255) / 256, 256, 0, stream>>>(
        x, Whi, Whf, Whc, Who, Wxi, Wxf, Wxc, Wxo,
        bxi, bhi, bxf, bhf, bxc, bhc, bxo, bho,
        W1, b1, W_halt, b_halt,
        A0, A1, cell, p_sum, ridx0, ridx1, cnt, (float*)d_out,
        Wg, bias_g, P, bias_p);

    PK pk;
    pk.Wg = Wg; pk.bias_g = bias_g; pk.P = P; pk.bias_p = bias_p;
    pk.W_halt = W_halt; pk.W2 = W2; pk.b2 = b2;
    pk.A0 = A0; pk.A1 = A1; pk.cell = cell; pk.p_sum = p_sum;
    pk.ridx0 = ridx0; pk.ridx1 = ridx1; pk.cnt = cnt; pk.outp = (float*)d_out;

    int occ = 0;
    if (hipOccupancyMaxActiveBlocksPerMultiprocessor(
            &occ, reinterpret_cast<const void*>(act_loop), 256, 0) != hipSuccess || occ < 1)
        occ = 4;
    int nblk = occ * 256;           // 256 CUs
    if (nblk > 1024) nblk = 1024;   // 4 blocks/CU target (LDS 33.8 KB)
    void* args[] = { (void*)&pk };
    hipLaunchCooperativeKernel(reinterpret_cast<const void*>(act_loop),
                               dim3(nblk), dim3(256), args, 0, stream);
}

// Round 6
// 534.931 us; speedup vs baseline: 1.6951x; 1.6951x over previous
//
#include <hip/hip_runtime.h>
#include <hip/hip_bf16.h>

#define BATCH 8192
#define IN_DIM 64
#define HID 1024
#define KTOT 1088   // HID + IN_DIM, fused K
#define NGATES 4096 // 4*HID, column c = 64*G + 16*g + q -> gate g of h=16*G+q
#define OMID 128
#define NP 256      // packed P rows (W1 0..127, W_halt 128, zeros)
#define MAX_ITER 8

#define TM 128
#define TN 128
#define TK 64
#define GY 32       // gates grid y (by-stride loop); 32*32=1024 blocks = 4/CU

typedef __attribute__((ext_vector_type(8))) short short8;
typedef __attribute__((ext_vector_type(4))) float float4v;

__device__ __forceinline__ float bf2f(short s) {
    union { float f; unsigned u; } v; v.u = ((unsigned)(unsigned short)s) << 16; return v.f;
}
__device__ __forceinline__ short f2bf(float f) {
    union { float f; unsigned u; } v; v.f = f;
    unsigned r = v.u + 0x7fff + ((v.u >> 16) & 1);  // round-to-nearest-even
    return (short)(r >> 16);
}
__device__ __forceinline__ float sigmoidf_(float x) {
    float xc = fminf(fmaxf(x, -30.f), 30.f);
    return 1.f / (1.f + __expf(-xc));
}
__device__ __forceinline__ float tanhf_(float x) {
    float xc = fminf(fmaxf(x, -15.f), 15.f);
    float e = __expf(2.f * xc);
    return (e - 1.f) / (e + 1.f);
}

// Gates GEMM + fused LSTM cell update. Rows indirected through compacted
// active list; by-stride loop over m-tiles (empty steps exit immediately).
// t=0 host-special-cased: A,B offset by HID, K=64 (state==0).
// LDS XOR swizzle (R2-verified: 0 bank conflicts); swizzle read offsets and
// staging pointers hoisted out of the K-loop (R4 showed VALUBusy 46% —
// k0-invariant address math was being recomputed every iteration).
__global__ __launch_bounds__(256) void gates_k(
    const short* __restrict__ A,
    const short* __restrict__ B,
    const float* __restrict__ bias_g,
    int K,
    float* __restrict__ cell, short* __restrict__ Aout,
    const int* __restrict__ ridx, const int* __restrict__ cnt, int t)
{
    __shared__ short As[TM * TK];
    __shared__ short Bs[TN * TK];
    const int n_act = cnt[t];
    const int tid  = threadIdx.x;
    const int wave = tid >> 6, lane = tid & 63;
    const int wm = wave & 1, wn = wave >> 1;
    const int colq = lane & 15, q = lane >> 4;
    const int lrow8 = lane >> 3;                    // row within 8-row region
    const int lk    = (((lane & 7) ^ lrow8) * 8);   // swizzled source k-chunk
    const int n0 = blockIdx.x * TN;

    // k0-invariant LDS read offsets (element units)
    int aoff[4][2], boff[4][2];
#pragma unroll
    for (int i = 0; i < 4; ++i) {
        const int Ra = wm * 64 + i * 16 + colq;
        const int Rb = wn * 64 + i * 16 + colq;
#pragma unroll
        for (int c2 = 0; c2 < 2; ++c2) {
            const int C = q + 4 * c2;
            aoff[i][c2] = Ra * TK + ((C ^ (Ra & 7)) << 3);
            boff[i][c2] = Rb * TK + ((C ^ (Rb & 7)) << 3);
        }
    }

    for (int by = blockIdx.y; by * TM < n_act; by += gridDim.y) {
        const int m0 = by * TM;

        float4v acc[4][4];
#pragma unroll
        for (int i = 0; i < 4; ++i)
#pragma unroll
            for (int j = 0; j < 4; ++j) acc[i][j] = (float4v)0.f;

        const short* ga[4];
        const short* gb[4];
#pragma unroll
        for (int it = 0; it < 4; ++it) {
            const int rr = (wave * 4 + it) * 8;
            ga[it] = A + (size_t)ridx[m0 + rr + lrow8] * KTOT + lk;
            gb[it] = B + (size_t)(n0 + rr + lrow8) * KTOT + lk;
        }

        for (int k0 = 0; k0 < K; k0 += TK) {
#pragma unroll
            for (int it = 0; it < 4; ++it) {
                const int rr = (wave * 4 + it) * 8;
                __builtin_amdgcn_global_load_lds(
                    (const __attribute__((address_space(1))) void*)ga[it],
                    (__attribute__((address_space(3))) void*)(As + rr * TK), 16, 0, 0);
                __builtin_amdgcn_global_load_lds(
                    (const __attribute__((address_space(1))) void*)gb[it],
                    (__attribute__((address_space(3))) void*)(Bs + rr * TK), 16, 0, 0);
                ga[it] += TK; gb[it] += TK;
            }
            __syncthreads();
#pragma unroll
            for (int c2 = 0; c2 < 2; ++c2) {
                short8 af[4], bf[4];
#pragma unroll
                for (int i = 0; i < 4; ++i) {
                    af[i] = *(const short8*)(As + aoff[i][c2]);
                    bf[i] = *(const short8*)(Bs + boff[i][c2]);
                }
#pragma unroll
                for (int i = 0; i < 4; ++i)
#pragma unroll
                    for (int j = 0; j < 4; ++j)
                        acc[i][j] = __builtin_amdgcn_mfma_f32_16x16x32_bf16(af[i], bf[j], acc[i][j], 0, 0, 0);
            }
            __syncthreads();
        }

        const int G = blockIdx.x * 2 + wn;   // 64-col group = 16 hidden units
        const int h = G * 16 + colq;
        const float bi  = bias_g[G * 64 +  0 + colq];
        const float bff = bias_g[G * 64 + 16 + colq];
        const float bc  = bias_g[G * 64 + 32 + colq];
        const float bo  = bias_g[G * 64 + 48 + colq];
#pragma unroll
        for (int i = 0; i < 4; ++i) {
            const int pbase = m0 + wm * 64 + i * 16 + q * 4;
#pragma unroll
            for (int r = 0; r < 4; ++r) {
                const int pos = pbase + r;
                if (pos < n_act) {
                    const int row = ridx[pos];
                    const float ig = sigmoidf_(acc[i][0][r] + bi);
                    const float fg = sigmoidf_(acc[i][1][r] + bff);
                    const float cg = tanhf_(acc[i][2][r] + bc);
                    const float og = sigmoidf_(acc[i][3][r] + bo);
                    const size_t ci = (size_t)row * HID + h;
                    const float c = fg * cell[ci] + ig * cg;
                    cell[ci] = c;
                    Aout[(size_t)row * KTOT + h] = f2bf(og * tanhf_(c));
                }
            }
        }
        __syncthreads();   // protect As/Bs before next m-tile
    }
}

// Fused mid GEMM (cols 0..127 = W1 only, no zero padding) + W2-dot via
// shuffle+LDS reduction + halt-dot (state·W_halt, fp32) + halting
// bookkeeping. One block per 128-row tile. Math validated in R5 Phase B.
__global__ __launch_bounds__(256) void midfin_k(
    const short* __restrict__ Anew,
    const short* __restrict__ P,       // W1 bf16 (ld=HID)
    const float* __restrict__ bias_p,  // b1[0..127], b_halt at [128]
    const float* __restrict__ W_halt, const float* __restrict__ W2,
    const float* __restrict__ b2,
    float* __restrict__ outp, float* __restrict__ p_sum,
    const int* __restrict__ ridx_cur, int* __restrict__ ridx_next,
    int* __restrict__ cnt, int t)
{
    __shared__ short As[TM * TK];
    __shared__ short Bs[TN * TK];
    __shared__ float red[2][2][4][4][4];   // [wn][wm][i][q][r]
    __shared__ float hbuf[TM];
    const int n_act = cnt[t];
    const int m0 = blockIdx.x * TM;
    if (m0 >= n_act) return;
    const int tid  = threadIdx.x;
    const int wave = tid >> 6, lane = tid & 63;
    const int wm = wave & 1, wn = wave >> 1;
    const int colq = lane & 15, q = lane >> 4;
    const int lrow8 = lane >> 3;
    const int lk    = (((lane & 7) ^ lrow8) * 8);

    // (1) halt-dot: per row, state · W_halt
    for (int s = 0; s < 32; ++s) {
        const int lr = wave * 32 + s;
        const int row = ridx_cur[m0 + lr];
        const short* Ar = Anew + (size_t)row * KTOT + lane * 16;
        const short8 v0 = *(const short8*)Ar;
        const short8 v1 = *(const short8*)(Ar + 8);
        const float* Wh = W_halt + lane * 16;
        float hv = 0.f;
#pragma unroll
        for (int e = 0; e < 8; ++e) hv += bf2f(v0[e]) * Wh[e];
#pragma unroll
        for (int e = 0; e < 8; ++e) hv += bf2f(v1[e]) * Wh[8 + e];
#pragma unroll
        for (int o = 32; o > 0; o >>= 1) hv += __shfl_down(hv, o);
        if (lane == 0) hbuf[lr] = hv;
    }

    // (2) mid GEMM: 128 rows x 128 cols, K=HID
    float4v acc[4][4];
#pragma unroll
    for (int i = 0; i < 4; ++i)
#pragma unroll
        for (int j = 0; j < 4; ++j) acc[i][j] = (float4v)0.f;

    const short* ga[4];
    const short* gb[4];
#pragma unroll
    for (int it = 0; it < 4; ++it) {
        const int rr = (wave * 4 + it) * 8;
        ga[it] = Anew + (size_t)ridx_cur[m0 + rr + lrow8] * KTOT + lk;
        gb[it] = P + (size_t)(rr + lrow8) * HID + lk;
    }
    int aoff[4][2], boff[4][2];
#pragma unroll
    for (int i = 0; i < 4; ++i) {
        const int Ra = wm * 64 + i * 16 + colq;
        const int Rb = wn * 64 + i * 16 + colq;
#pragma unroll
        for (int c2 = 0; c2 < 2; ++c2) {
            const int C = q + 4 * c2;
            aoff[i][c2] = Ra * TK + ((C ^ (Ra & 7)) << 3);
            boff[i][c2] = Rb * TK + ((C ^ (Rb & 7)) << 3);
        }
    }

    for (int k0 = 0; k0 < HID; k0 += TK) {
#pragma unroll
        for (int it = 0; it < 4; ++it) {
            const int rr = (wave * 4 + it) * 8;
            __builtin_amdgcn_global_load_lds(
                (const __attribute__((address_space(1))) void*)ga[it],
                (__attribute__((address_space(3))) void*)(As + rr * TK), 16, 0, 0);
            __builtin_amdgcn_global_load_lds(
                (const __attribute__((address_space(1))) void*)gb[it],
                (__attribute__((address_space(3))) void*)(Bs + rr * TK), 16, 0, 0);
            ga[it] += TK; gb[it] += TK;
        }
        __syncthreads();
#pragma unroll
        for (int c2 = 0; c2 < 2; ++c2) {
            short8 af[4], bf[4];
#pragma unroll
            for (int i = 0; i < 4; ++i) {
                af[i] = *(const short8*)(As + aoff[i][c2]);
                bf[i] = *(const short8*)(Bs + boff[i][c2]);
            }
#pragma unroll
            for (int i = 0; i < 4; ++i)
#pragma unroll
                for (int j = 0; j < 4; ++j)
                    acc[i][j] = __builtin_amdgcn_mfma_f32_16x16x32_bf16(af[i], bf[j], acc[i][j], 0, 0, 0);
        }
        __syncthreads();
    }

    // (3) epilogue: relu + W2-dot, reduce over cols
    float pr[4][4];
#pragma unroll
    for (int i = 0; i < 4; ++i)
#pragma unroll
        for (int r = 0; r < 4; ++r) pr[i][r] = 0.f;
#pragma unroll
    for (int j = 0; j < 4; ++j) {
        const int col = wn * 64 + j * 16 + colq;
        const float b = bias_p[col];
        const float w2 = W2[col];
#pragma unroll
        for (int i = 0; i < 4; ++i)
#pragma unroll
            for (int r = 0; r < 4; ++r)
                pr[i][r] += fmaxf(acc[i][j][r] + b, 0.f) * w2;
    }
#pragma unroll
    for (int i = 0; i < 4; ++i)
#pragma unroll
        for (int r = 0; r < 4; ++r) {
            float v = pr[i][r];
            v += __shfl_down(v, 8, 16);
            v += __shfl_down(v, 4, 16);
            v += __shfl_down(v, 2, 16);
            v += __shfl_down(v, 1, 16);
            if (colq == 0) red[wn][wm][i][q][r] = v;
        }
    __syncthreads();

    // (4) finalize: one thread per row
    if (tid < TM) {
        const int pos = m0 + tid;
        if (pos < n_act) {
            const int lwm = tid >> 6, i = (tid >> 4) & 3, lq = (tid >> 2) & 3, r = tid & 3;
            const float odot = red[0][lwm][i][lq][r] + red[1][lwm][i][lq][r];
            const int row = ridx_cur[pos];
            const float ov = sigmoidf_(odot + b2[0]);
            const float h  = sigmoidf_(hbuf[tid] + bias_p[OMID]);
            const float ps = p_sum[row];
            const float pn = ps + h;
            const bool fin = (pn >= 1.f - 1e-3f) || (t == MAX_ITER - 1);
            const float halt = fin ? (1.f - ps) : h;
            outp[row] += ov * halt;
            p_sum[row] = fin ? 1.f : pn;
            if (!fin) {
                const int d = atomicAdd(&cnt[t + 1], 1);
                ridx_next[d] = row;
            }
        }
    }
}

// one dispatch for all setup: weight packing + A/cell/bookkeeping init
#define SETUP_INIT  (BATCH * KTOT)
#define SETUP_WG    (NGATES * KTOT)
#define SETUP_P     (NP * HID)
#define SETUP_TOT   (SETUP_INIT + SETUP_WG + SETUP_P)
__global__ __launch_bounds__(256) void setup_k(
    const float* __restrict__ x,
    const float* __restrict__ Whi, const float* __restrict__ Whf,
    const float* __restrict__ Whc, const float* __restrict__ Who,
    const float* __restrict__ Wxi, const float* __restrict__ Wxf,
    const float* __restrict__ Wxc, const float* __restrict__ Wxo,
    const float* __restrict__ bxi, const float* __restrict__ bhi,
    const float* __restrict__ bxf, const float* __restrict__ bhf,
    const float* __restrict__ bxc, const float* __restrict__ bhc,
    const float* __restrict__ bxo, const float* __restrict__ bho,
    const float* __restrict__ W1, const float* __restrict__ b1,
    const float* __restrict__ W_halt, const float* __restrict__ b_halt,
    short* __restrict__ A0, short* __restrict__ A1,
    float* __restrict__ cell, float* __restrict__ p_sum,
    int* __restrict__ ridx0, int* __restrict__ ridx1, int* __restrict__ cnt,
    float* __restrict__ outp,
    short* __restrict__ Wg, float* __restrict__ bias_g,
    short* __restrict__ P, float* __restrict__ bias_p)
{
    int idx = blockIdx.x * 256 + threadIdx.x;
    if (idx < SETUP_INIT) {
        const int row = idx / KTOT, k = idx - row * KTOT;
        const short v = (k < HID) ? (short)0 : f2bf(x[row * IN_DIM + (k - HID)]);
        A0[idx] = v;
        A1[idx] = v;   // x cols iteration-invariant; state part overwritten each step
        if (k < HID) cell[(size_t)row * HID + k] = 0.f;
        if (k == 0) {
            p_sum[row] = 0.f;
            outp[row] = 0.f;
            ridx0[row] = row;   // step 0: identity compaction
            ridx1[row] = 0;     // in-range dummies for padded tile reads
        }
        if (row == 0 && k <= MAX_ITER) cnt[k] = (k == 0) ? BATCH : 0;
        return;
    }
    idx -= SETUP_INIT;
    if (idx < SETUP_WG) {
        const int n = idx / KTOT, k = idx - n * KTOT;
        // interleaved layout: n = 64*G + 16*g + q  ->  gate g of hidden h=16*G+q
        const int G = n >> 6, g = (n >> 4) & 3, q = n & 15;
        const int h = G * 16 + q;
        const float* Wh = (g == 0) ? Whi : (g == 1) ? Whf : (g == 2) ? Whc : Who;
        const float* Wx = (g == 0) ? Wxi : (g == 1) ? Wxf : (g == 2) ? Wxc : Wxo;
        const float v = (k < HID) ? Wh[h * HID + k] : Wx[h * IN_DIM + (k - HID)];
        Wg[idx] = f2bf(v);
        if (k == 0) {
            const float* bx = (g == 0) ? bxi : (g == 1) ? bxf : (g == 2) ? bxc : bxo;
            const float* bh = (g == 0) ? bhi : (g == 1) ? bhf : (g == 2) ? bhc : bho;
            bias_g[n] = bx[h] + bh[h];
        }
        return;
    }
    idx -= SETUP_WG;
    if (idx < SETUP_P) {
        const int n = idx >> 10, k = idx & 1023;
        const float v = (n < OMID) ? W1[n * HID + k] : (n == OMID ? W_halt[k] : 0.f);
        P[idx] = f2bf(v);
        if (k == 0) bias_p[n] = (n < OMID) ? b1[n] : (n == OMID ? b_halt[0] : 0.f);
    }
}

extern "C" void kernel_launch(void* const* d_in, const int* in_sizes, int n_in,
                              void* d_out, int out_size, void* d_ws, size_t ws_size,
                              hipStream_t stream) {
    const float* x    = (const float*)d_in[0];
    const float* Wxi  = (const float*)d_in[1];
    const float* bxi  = (const float*)d_in[2];
    const float* Whi  = (const float*)d_in[3];
    const float* bhi  = (const float*)d_in[4];
    const float* Wxf  = (const float*)d_in[5];
    const float* bxf  = (const float*)d_in[6];
    const float* Whf  = (const float*)d_in[7];
    const float* bhf  = (const float*)d_in[8];
    const float* Wxc  = (const float*)d_in[9];
    const float* bxc  = (const float*)d_in[10];
    const float* Whc  = (const float*)d_in[11];
    const float* bhc  = (const float*)d_in[12];
    const float* Wxo  = (const float*)d_in[13];
    const float* bxo  = (const float*)d_in[14];
    const float* Who  = (const float*)d_in[15];
    const float* bho  = (const float*)d_in[16];
    const float* W_halt = (const float*)d_in[17];
    const float* b_halt = (const float*)d_in[18];
    const float* W1   = (const float*)d_in[19];
    const float* b1   = (const float*)d_in[20];
    const float* W2   = (const float*)d_in[21];
    const float* b2   = (const float*)d_in[22];

    char* p = (char*)d_ws;
    auto carve = [&](size_t bytes) { char* r = p; p += (bytes + 255) & ~(size_t)255; return r; };
    short* A0     = (short*)carve((size_t)BATCH * KTOT * 2);
    short* A1     = (short*)carve((size_t)BATCH * KTOT * 2);
    short* Wg     = (short*)carve((size_t)NGATES * KTOT * 2);
    float* bias_g = (float*)carve((size_t)NGATES * 4);
    short* P      = (short*)carve((size_t)NP * HID * 2);
    float* bias_p = (float*)carve((size_t)NP * 4);
    float* cell   = (float*)carve((size_t)BATCH * HID * 4);
    float* p_sum  = (float*)carve((size_t)BATCH * 4);
    int*   ridx0  = (int*)carve((size_t)BATCH * 4);
    int*   ridx1  = (int*)carve((size_t)BATCH * 4);
    int*   cnt    = (int*)carve((size_t)(MAX_ITER + 1) * 4);

    setup_k<<<(SETUP_TOT + 255) / 256, 256, 0, stream>>>(
        x, Whi, Whf, Whc, Who, Wxi, Wxf, Wxc, Wxo,
        bxi, bhi, bxf, bhf, bxc, bhc, bxo, bho,
        W1, b1, W_halt, b_halt,
        A0, A1, cell, p_sum, ridx0, ridx1, cnt, (float*)d_out,
        Wg, bias_g, P, bias_p);

    for (int t = 0; t < MAX_ITER; ++t) {
        const short* Ain = (t & 1) ? A1 : A0;
        short*       Aot = (t & 1) ? A0 : A1;
        const int* rc = (t & 1) ? ridx1 : ridx0;
        int*       rn = (t & 1) ? ridx0 : ridx1;
        if (t == 0) {
            // state==0: only the x-part (K=64) of the fused K contributes.
            gates_k<<<dim3(NGATES / TN, GY), 256, 0, stream>>>(
                Ain + HID, Wg + HID, bias_g, IN_DIM, cell, Aot, rc, cnt, t);
        } else {
            gates_k<<<dim3(NGATES / TN, GY), 256, 0, stream>>>(
                Ain, Wg, bias_g, KTOT, cell, Aot, rc, cnt, t);
        }
        midfin_k<<<BATCH / TM, 256, 0, stream>>>(
            Aot, P, bias_p, W_halt, W2, b2, (float*)d_out, p_sum, rc, rn, cnt, t);
    }
}